// Round 1
// baseline (260.201 us; speedup 1.0000x reference)
//
#include <hip/hip_runtime.h>
#include <math.h>

#define BATCH 4096
#define DIM   32
#define KNB   16
#define PAD   33   // padded leading dim for [*, 32] LDS tiles (bank-conflict break)

// One block (256 threads) per batch element.
//
// Phases:
//  1. stage rel_w(32x32), W(32x32), b, user vec, e0, hop-1 ids into LDS
//  2. gather hop-2 ids; stage hop-1 entity embeddings e1[16][32]
//  3. attention scores: sc2[256] = user . rel_w[rel2[j]]  (thread j),
//     sc1[16]  = user . rel_w[rel1[k]]  (threads 0..15)
//  4. softmax over K=16 (redundant per-thread reduce within each 16-group)
//  5. hop-1: agg over 16 gathered neighbor rows (lane-per-dim, coalesced),
//     then 32x32 linear from LDS, sigmoid -> h1[16][32]
//  6. hop-0 iter-0: agg over e1 (already in LDS), linear, sigmoid -> h0
//  7. hop-0 iter-1: agg over h1 with the SAME attn1, linear, tanh -> item
//  8. out[b] = sigmoid(user . item)   (shuffle-reduce over 32 lanes)

__global__ __launch_bounds__(256) void kgcn_kernel(
    const int*   __restrict__ u,
    const int*   __restrict__ v,
    const float* __restrict__ usr_w,
    const float* __restrict__ ent_w,
    const float* __restrict__ rel_w,
    const float* __restrict__ W,
    const float* __restrict__ bvec,
    const int*   __restrict__ adj_ent,
    const int*   __restrict__ adj_rel,
    float*       __restrict__ out)
{
    __shared__ float relw_s[DIM * PAD];
    __shared__ float Ws[DIM * PAD];
    __shared__ float b_s[DIM];
    __shared__ float user_s[DIM];
    __shared__ float e0_s[DIM];
    __shared__ int   ent1_s[KNB], rel1_s[KNB];
    __shared__ int   ent2_s[KNB * KNB], rel2_s[KNB * KNB];
    __shared__ float e1_s[KNB * PAD];
    __shared__ float sc2_s[KNB * 17];
    __shared__ float attn2_s[KNB * 17];
    __shared__ float sc1_s[KNB];
    __shared__ float attn1_s[KNB];
    __shared__ float tmp_s[KNB * PAD];
    __shared__ float h1_s[KNB * PAD];
    __shared__ float tmp0_s[DIM];
    __shared__ float h0_s[DIM];

    const int t  = threadIdx.x;
    const int bb = blockIdx.x;

    // ---- phase 1: stage weights + per-batch vectors -------------------------
    #pragma unroll
    for (int i = 0; i < 4; ++i) {
        int idx = t + i * 256;            // 0..1023, coalesced
        int r = idx >> 5, d = idx & 31;
        relw_s[r * PAD + d] = rel_w[idx];
        Ws[r * PAD + d]     = W[idx];
    }
    const int vid = v[bb];
    if (t < 32) {
        user_s[t] = usr_w[(size_t)u[bb] * DIM + t];
        if (t == 0) { }  // b staged below by lane group
    } else if (t < 64) {
        e0_s[t - 32] = ent_w[(size_t)vid * DIM + (t - 32)];
    } else if (t < 80) {
        ent1_s[t - 64] = adj_ent[(size_t)vid * KNB + (t - 64)];
    } else if (t < 96) {
        rel1_s[t - 80] = adj_rel[(size_t)vid * KNB + (t - 80)];
    } else if (t < 128) {
        b_s[t - 96] = bvec[t - 96];
    }
    __syncthreads();

    // ---- phase 2: hop-2 ids + stage e1 --------------------------------------
    {
        int parent = ent1_s[t >> 4];
        ent2_s[t] = adj_ent[(size_t)parent * KNB + (t & 15)];
        rel2_s[t] = adj_rel[(size_t)parent * KNB + (t & 15)];
    }
    #pragma unroll
    for (int i = 0; i < 2; ++i) {
        int idx = t + i * 256;            // 0..511
        int n = idx >> 5, d = idx & 31;
        e1_s[n * PAD + d] = ent_w[(size_t)ent1_s[n] * DIM + d];
    }
    __syncthreads();

    // ---- phase 3: attention scores ------------------------------------------
    {
        int r = rel2_s[t];
        float s = 0.f;
        #pragma unroll
        for (int d = 0; d < DIM; ++d) s += user_s[d] * relw_s[r * PAD + d];
        sc2_s[(t >> 4) * 17 + (t & 15)] = s;
    }
    if (t < KNB) {
        int r = rel1_s[t];
        float s = 0.f;
        #pragma unroll
        for (int d = 0; d < DIM; ++d) s += user_s[d] * relw_s[r * PAD + d];
        sc1_s[t] = s;
    }
    __syncthreads();

    // ---- phase 4: softmax over K=16 -----------------------------------------
    {
        int n = t >> 4;
        float mx = -1e30f;
        #pragma unroll
        for (int k = 0; k < KNB; ++k) mx = fmaxf(mx, sc2_s[n * 17 + k]);
        float sum = 0.f;
        #pragma unroll
        for (int k = 0; k < KNB; ++k) sum += expf(sc2_s[n * 17 + k] - mx);
        attn2_s[n * 17 + (t & 15)] = expf(sc2_s[n * 17 + (t & 15)] - mx) / sum;
    }
    if (t < KNB) {
        float mx = -1e30f;
        #pragma unroll
        for (int k = 0; k < KNB; ++k) mx = fmaxf(mx, sc1_s[k]);
        float sum = 0.f;
        #pragma unroll
        for (int k = 0; k < KNB; ++k) sum += expf(sc1_s[k] - mx);
        attn1_s[t] = expf(sc1_s[t] - mx) / sum;
    }
    __syncthreads();

    // ---- phase 5: hop-1 aggregate + linear + sigmoid ------------------------
    #pragma unroll
    for (int ro = 0; ro < 2; ++ro) {
        int n = (t >> 5) + ro * 8;        // node 0..15
        int d = t & 31;                   // dim
        float agg = 0.f;
        #pragma unroll
        for (int k = 0; k < KNB; ++k) {
            // coalesced: 32 lanes of a dim-group read one 128B ent_w row
            agg += attn2_s[n * 17 + k] *
                   ent_w[(size_t)ent2_s[n * KNB + k] * DIM + d];
        }
        tmp_s[n * PAD + d] = e1_s[n * PAD + d] + agg;
    }
    __syncthreads();
    #pragma unroll
    for (int ro = 0; ro < 2; ++ro) {
        int n = (t >> 5) + ro * 8;
        int o = t & 31;
        float h = b_s[o];
        #pragma unroll
        for (int d = 0; d < DIM; ++d) h += tmp_s[n * PAD + d] * Ws[o * PAD + d];
        h1_s[n * PAD + o] = 1.f / (1.f + expf(-h));
    }
    __syncthreads();

    // ---- phase 6: hop-0 iter-0 ----------------------------------------------
    if (t < 32) {
        float agg = 0.f;
        #pragma unroll
        for (int k = 0; k < KNB; ++k) agg += attn1_s[k] * e1_s[k * PAD + t];
        tmp0_s[t] = e0_s[t] + agg;
    }
    __syncthreads();
    if (t < 32) {
        float h = b_s[t];
        #pragma unroll
        for (int d = 0; d < DIM; ++d) h += tmp0_s[d] * Ws[t * PAD + d];
        h0_s[t] = 1.f / (1.f + expf(-h));
    }
    __syncthreads();

    // ---- phase 7: hop-0 iter-1 (attn1 reused) -------------------------------
    if (t < 32) {
        float agg = 0.f;
        #pragma unroll
        for (int k = 0; k < KNB; ++k) agg += attn1_s[k] * h1_s[k * PAD + t];
        tmp0_s[t] = h0_s[t] + agg;
    }
    __syncthreads();
    if (t < 32) {
        float h = b_s[t];
        #pragma unroll
        for (int d = 0; d < DIM; ++d) h += tmp0_s[d] * Ws[t * PAD + d];
        float item = tanhf(h);
        float p = user_s[t] * item;
        #pragma unroll
        for (int off = 16; off; off >>= 1) p += __shfl_down(p, off, 32);
        if (t == 0) out[bb] = 1.f / (1.f + expf(-p));
    }
}

extern "C" void kernel_launch(void* const* d_in, const int* in_sizes, int n_in,
                              void* d_out, int out_size, void* d_ws, size_t ws_size,
                              hipStream_t stream) {
    const int*   u       = (const int*)d_in[0];
    const int*   v       = (const int*)d_in[1];
    const float* usr_w   = (const float*)d_in[2];
    const float* ent_w   = (const float*)d_in[3];
    const float* rel_w   = (const float*)d_in[4];
    const float* W       = (const float*)d_in[5];
    const float* bvec    = (const float*)d_in[6];
    const int*   adj_ent = (const int*)d_in[7];
    const int*   adj_rel = (const int*)d_in[8];
    float* out = (float*)d_out;

    kgcn_kernel<<<BATCH, 256, 0, stream>>>(u, v, usr_w, ent_w, rel_w, W, bvec,
                                           adj_ent, adj_rel, out);
}

// Round 3
// 259.231 us; speedup vs baseline: 1.0037x; 1.0037x over previous
//
#include <hip/hip_runtime.h>
#include <math.h>

#define BATCH 4096
#define DIM   32
#define KNB   16
#define PADW  33   // pad for [32][32] weight tile (o*33+d: conflict-free across o)
#define PADV  34   // even pad for float2 rows (k*34+t: conflict-free across t)

// One 256-thread block per batch element.
// Key algebra: attention scores depend only on (user, relation-id) and there
// are 32 relations -> compute sc[32] once per block, all 272 scores are LDS
// lookups. Softmax is wave-parallel (shfl_xor butterflies over 16-groups),
// one __expf per thread. Hop-2 embedding gathers are float2 per (node,
// dim-pair) thread, all 16 issued into registers before softmax compute so
// HBM/L3 latency hides under VALU work.

__global__ __launch_bounds__(256, 4) void kgcn_kernel(
    const int*   __restrict__ u,
    const int*   __restrict__ v,
    const float* __restrict__ usr_w,
    const float* __restrict__ ent_w,
    const float* __restrict__ rel_w,
    const float* __restrict__ W,
    const float* __restrict__ bvec,
    const int*   __restrict__ adj_ent,
    const int*   __restrict__ adj_rel,
    float*       __restrict__ out)
{
    __shared__ float Ws[DIM * PADW];
    __shared__ float user_s[DIM], e0_s[DIM], b_s[DIM], sc_s[DIM];
    __shared__ int   ent1_s[KNB], rel1_s[KNB];
    __shared__ int   eoff2_s[KNB * KNB];      // entity-id * 32 (float offset)
    __shared__ float e1_s[KNB * PADV];
    __shared__ float attn2_s[KNB * 17];
    __shared__ float attn1_s[KNB];
    __shared__ float tmp_s[KNB * PADV];
    __shared__ float h1_s[KNB * PADV];
    __shared__ float tmp0_s[DIM];

    const int t  = threadIdx.x;
    const int bb = blockIdx.x;
    const int vid = v[bb];

    // ---- P1: stage W, b, user, e0, hop-1 ids --------------------------------
    #pragma unroll
    for (int i = 0; i < 4; ++i) {
        int idx = t + i * 256;                       // coalesced
        Ws[(idx >> 5) * PADW + (idx & 31)] = W[idx];
    }
    if (t < 32) {
        user_s[t] = usr_w[u[bb] * DIM + t];
    } else if (t < 64) {
        e0_s[t - 32] = ent_w[vid * DIM + (t - 32)];
    } else if (t < 80) {
        ent1_s[t - 64] = adj_ent[vid * KNB + (t - 64)];
    } else if (t < 96) {
        rel1_s[t - 80] = adj_rel[vid * KNB + (t - 80)];
    } else if (t < 128) {
        b_s[t - 96] = bvec[t - 96];
    }
    __syncthreads();

    // ---- P2: hop-2 ids + per-relation scores sc[32] -------------------------
    int rel2;
    {
        int parent = ent1_s[t >> 4];
        rel2       = adj_rel[parent * KNB + (t & 15)];
        eoff2_s[t] = adj_ent[parent * KNB + (t & 15)] * DIM;
    }
    if (t < 32) {
        const float* rw = rel_w + t * DIM;
        float s = 0.f;
        #pragma unroll
        for (int d = 0; d < DIM; ++d) s += user_s[d] * rw[d];
        sc_s[t] = s;
    }
    __syncthreads();

    // ---- P3: issue all hop-2/hop-1 embedding loads; wave-parallel softmax ---
    const int n  = t >> 4;        // node 0..15
    const int d2 = t & 15;        // dim-pair 0..15  (also k-slot for softmax)
    const float2* ew2 = (const float2*)ent_w;

    float2 vbuf[KNB];
    #pragma unroll
    for (int k = 0; k < KNB; ++k)
        vbuf[k] = ew2[(eoff2_s[n * KNB + k] >> 1) + d2];
    float2 ev = ew2[ent1_s[n] * (DIM / 2) + d2];
    *(float2*)&e1_s[n * PADV + 2 * d2] = ev;

    // softmax over k (=d2) within each node's 16-lane group
    {
        float s2 = sc_s[rel2];
        float m = s2;
        #pragma unroll
        for (int msk = 1; msk < 16; msk <<= 1) m = fmaxf(m, __shfl_xor(m, msk, 16));
        float p = __expf(s2 - m);
        float q = p;
        #pragma unroll
        for (int msk = 1; msk < 16; msk <<= 1) q += __shfl_xor(q, msk, 16);
        attn2_s[n * 17 + d2] = p / q;
    }
    if (t < KNB) {
        float s1 = sc_s[rel1_s[t]];
        float m = s1;
        #pragma unroll
        for (int msk = 1; msk < 16; msk <<= 1) m = fmaxf(m, __shfl_xor(m, msk, 16));
        float p = __expf(s1 - m);
        float q = p;
        #pragma unroll
        for (int msk = 1; msk < 16; msk <<= 1) q += __shfl_xor(q, msk, 16);
        attn1_s[t] = p / q;
    }
    __syncthreads();

    // ---- P4: hop-1 weighted aggregate (registers) ---------------------------
    {
        float2 a = make_float2(0.f, 0.f);
        #pragma unroll
        for (int k = 0; k < KNB; ++k) {
            float w = attn2_s[n * 17 + k];
            a.x += w * vbuf[k].x;
            a.y += w * vbuf[k].y;
        }
        float2 tv = make_float2(ev.x + a.x, ev.y + a.y);
        *(float2*)&tmp_s[n * PADV + 2 * d2] = tv;
    }
    __syncthreads();

    // ---- P5: hop-1 linear + sigmoid; hop-0 aggregate ------------------------
    #pragma unroll
    for (int ro = 0; ro < 2; ++ro) {
        int nn = (t >> 5) + 8 * ro;
        int o  = t & 31;
        float h = b_s[o];
        #pragma unroll
        for (int d = 0; d < DIM; ++d) h += tmp_s[nn * PADV + d] * Ws[o * PADW + d];
        h1_s[nn * PADV + o] = 1.f / (1.f + __expf(-h));
    }
    if (t < 32) {
        float a0 = 0.f;
        #pragma unroll
        for (int k = 0; k < KNB; ++k) a0 += attn1_s[k] * e1_s[k * PADV + t];
        tmp0_s[t] = e0_s[t] + a0;
    }
    __syncthreads();

    // ---- P6: hop-0 iter-0 linear; hop-0 iter-1 aggregate --------------------
    if (t < 32) {
        float h = b_s[t];
        #pragma unroll
        for (int d = 0; d < DIM; ++d) h += tmp0_s[d] * Ws[t * PADW + d];
        float h0 = 1.f / (1.f + __expf(-h));
        float a1 = 0.f;
        #pragma unroll
        for (int k = 0; k < KNB; ++k) a1 += attn1_s[k] * h1_s[k * PADV + t];
        tmp0_s[t] = h0 + a1;     // same-wave read-then-write: reads above done
    }
    __syncthreads();

    // ---- P7: final linear + tanh + user.item + sigmoid ----------------------
    if (t < 32) {
        float h = b_s[t];
        #pragma unroll
        for (int d = 0; d < DIM; ++d) h += tmp0_s[d] * Ws[t * PADW + d];
        float item = tanhf(h);
        float p = user_s[t] * item;
        #pragma unroll
        for (int off = 16; off; off >>= 1) p += __shfl_down(p, off, 32);
        if (t == 0) out[bb] = 1.f / (1.f + __expf(-p));
    }
}

extern "C" void kernel_launch(void* const* d_in, const int* in_sizes, int n_in,
                              void* d_out, int out_size, void* d_ws, size_t ws_size,
                              hipStream_t stream) {
    const int*   u       = (const int*)d_in[0];
    const int*   v       = (const int*)d_in[1];
    const float* usr_w   = (const float*)d_in[2];
    const float* ent_w   = (const float*)d_in[3];
    const float* rel_w   = (const float*)d_in[4];
    const float* W       = (const float*)d_in[5];
    const float* bvec    = (const float*)d_in[6];
    const int*   adj_ent = (const int*)d_in[7];
    const int*   adj_rel = (const int*)d_in[8];
    float* out = (float*)d_out;

    kgcn_kernel<<<BATCH, 256, 0, stream>>>(u, v, usr_w, ent_w, rel_w, W, bvec,
                                           adj_ent, adj_rel, out);
}